// Round 17
// baseline (569.350 us; speedup 1.0000x reference)
//
#include <hip/hip_runtime.h>
#include <hip/hip_bf16.h>
#include <math.h>
#include <string.h>

#define N_NODES 50000
#define E_EDGES 800000
#define M_PATHS 3
#define IN_F    128
#define H_HEADS 8
#define O_DIM   32
#define D_DIM   256   // H*O
#define HID_DIM 128
#define NEG_SLOPE 0.2f
#define NRANGE   64
#define RSZ      782                   // ceil(50000/64)
#define NCLASS   (M_PATHS * NRANGE)    // 192
#define CAP2     16384
#define CHUNK    2048
#define NCHUNK   ((E_EDGES + CHUNK - 1) / CHUNK)   // 391
#define TBLK     171                   // transpose blocks per metapath row
#define GEMM_BX  ((N_NODES + 63) / 64) // 782

typedef __attribute__((ext_vector_type(8))) short bf16x8;
typedef __attribute__((ext_vector_type(4))) float f32x4;

__device__ __forceinline__ float bflo(unsigned w) { return __uint_as_float(w << 16); }
__device__ __forceinline__ float bfhi(unsigned w) { return __uint_as_float(w & 0xffff0000u); }

__device__ __forceinline__ unsigned short f2bf(float f) {
    __hip_bfloat16 hb = __float2bfloat16(f);
    unsigned short us;
    memcpy(&us, &hb, 2);
    return us;
}
__device__ __forceinline__ unsigned pk_bf16(float a, float b) {
    return (unsigned)f2bf(a) | ((unsigned)f2bf(b) << 16);
}
__device__ __forceinline__ float fast_tanh(float x) {
    float e = __expf(2.f * x);        // |x| < ~6 here; no overflow
    return (e - 1.f) / (e + 1.f);
}

__device__ __forceinline__ bf16x8 cvt_frag(const float* __restrict__ p) {
    union { unsigned short u[8]; bf16x8 v; } r;
    const float4 f0 = *reinterpret_cast<const float4*>(p);
    const float4 f1 = *reinterpret_cast<const float4*>(p + 4);
    r.u[0] = f2bf(f0.x); r.u[1] = f2bf(f0.y); r.u[2] = f2bf(f0.z); r.u[3] = f2bf(f0.w);
    r.u[4] = f2bf(f1.x); r.u[5] = f2bf(f1.y); r.u[6] = f2bf(f1.z); r.u[7] = f2bf(f1.w);
    return r.v;
}
__device__ __forceinline__ bf16x8 zero_frag() {
    union { unsigned short u[8]; bf16x8 v; } r = {};
    return r.v;
}

// ======= prep: partition_edges (x < NCHUNK) + weight transposes (x >= NCHUNK) =======
__global__ __launch_bounds__(256) void prep(const int* __restrict__ eidx,
                                            const float* __restrict__ W,
                                            const float* __restrict__ W1,
                                            int* __restrict__ pcur,
                                            long long* __restrict__ pairs,
                                            unsigned short* __restrict__ Wt,
                                            unsigned short* __restrict__ W1t) {
    const int m = blockIdx.y;
    if (blockIdx.x < NCHUNK) {
        const int e0 = blockIdx.x * CHUNK;
        const int n = min(CHUNK, E_EDGES - e0);
        const int* src = eidx + (size_t)m * 2 * E_EDGES;
        const int* dst = src + E_EDGES;

        __shared__ int lcnt[NRANGE], lbase[NRANGE], lidx[NRANGE];
        for (int i = threadIdx.x; i < NRANGE; i += 256) lcnt[i] = 0;
        __syncthreads();

        int ss[8], cs[8];
        #pragma unroll
        for (int k = 0; k < 8; k++) {
            int o = k * 256 + threadIdx.x;
            if (o < n) {
                int e = e0 + o;
                int d = __builtin_nontemporal_load(dst + e);
                int s = __builtin_nontemporal_load(src + e);
                int c = d / RSZ;
                ss[k] = s; cs[k] = c | (d << 8);
                atomicAdd(&lcnt[c], 1);
            } else cs[k] = -1;
        }
        __syncthreads();
        for (int i = threadIdx.x; i < NRANGE; i += 256) {
            int cnt = lcnt[i];
            lbase[i] = (cnt > 0) ? atomicAdd(&pcur[m * NRANGE + i], cnt) : 0;
            lidx[i] = 0;
        }
        __syncthreads();
        #pragma unroll
        for (int k = 0; k < 8; k++) {
            if (cs[k] >= 0) {
                int c = cs[k] & 63;
                int d = cs[k] >> 8;
                int slot = lbase[c] + atomicAdd(&lidx[c], 1);
                if (slot < CAP2) {
                    long long p = ((long long)ss[k] << 32) | (unsigned)d;
                    pairs[(size_t)(m * NRANGE + c) * CAP2 + slot] = p;
                }
            }
        }
    } else {
        int t = blockIdx.x - NCHUNK + TBLK * m;
        if (t < 384) {              // W[m'] : [128][256] -> Wt[m'] : [256][128]
            int i = t * 256 + threadIdx.x;
            int mm = i >> 15, r = i & 32767;
            int k = r >> 8, c = r & 255;
            Wt[(size_t)mm * 32768 + c * IN_F + k] = f2bf(W[i]);
        } else if (t < 512) {       // sem_W1 : [256][128] -> W1t : [128][256]
            int r = (t - 384) * 256 + threadIdx.x;
            int k = r >> 7, c = r & 127;
            W1t[c * D_DIM + k] = f2bf(W1[r]);
        }
    }
}

// ======= gemm (+attn epilogue) for x < GEMM_BX; bucket_sort for x >= GEMM_BX =======
__global__ __launch_bounds__(256) void gemm_bucket(const float* __restrict__ hall,
                                                   const unsigned short* __restrict__ Wtall,
                                                   const float* __restrict__ attn_l,
                                                   const float* __restrict__ attn_r,
                                                   unsigned short* __restrict__ featb3,
                                                   float* __restrict__ el3,
                                                   float* __restrict__ er3,
                                                   const long long* __restrict__ pairs,
                                                   const int* __restrict__ pcur,
                                                   int* __restrict__ bsrc,
                                                   int* __restrict__ rs3,
                                                   int* __restrict__ re3) {
    const int my = blockIdx.y;
    if (blockIdx.x < GEMM_BX) {
        const float* h = hall + (size_t)my * N_NODES * IN_F;
        const unsigned short* Wt = Wtall + (size_t)my * D_DIM * IN_F;
        unsigned short* featb = featb3 + (size_t)my * N_NODES * D_DIM;
        float* el = el3 + (size_t)my * N_NODES * H_HEADS;
        float* er = er3 + (size_t)my * N_NODES * H_HEADS;

        const int wave = threadIdx.x >> 6;
        const int lane = threadIdx.x & 63;
        const int l15 = lane & 15, lhi = lane >> 4;
        const int r0 = blockIdx.x * 64;
        const int c0 = wave * 64;
        f32x4 acc[4][4] = {};

        for (int ks = 0; ks < 4; ++ks) {
            bf16x8 a[4], b[4];
            #pragma unroll
            for (int rg = 0; rg < 4; rg++) {
                int row = r0 + rg * 16 + l15;
                a[rg] = (row < N_NODES) ? cvt_frag(h + (size_t)row * IN_F + ks * 32 + lhi * 8)
                                        : zero_frag();
            }
            #pragma unroll
            for (int ct = 0; ct < 4; ct++) {
                int col = c0 + ct * 16 + l15;
                b[ct] = *reinterpret_cast<const bf16x8*>(Wt + (size_t)col * IN_F + ks * 32 + lhi * 8);
            }
            #pragma unroll
            for (int rg = 0; rg < 4; rg++)
                #pragma unroll
                for (int ct = 0; ct < 4; ct++)
                    acc[rg][ct] = __builtin_amdgcn_mfma_f32_16x16x32_bf16(a[rg], b[ct], acc[rg][ct], 0, 0, 0);
        }
        #pragma unroll
        for (int rg = 0; rg < 4; rg++) {
            #pragma unroll
            for (int reg = 0; reg < 4; reg++) {
                int row = r0 + rg * 16 + lhi * 4 + reg;
                if (row < N_NODES) {
                    #pragma unroll
                    for (int ct = 0; ct < 4; ct++) {
                        int col = c0 + ct * 16 + l15;
                        featb[(size_t)row * D_DIM + col] = f2bf(acc[rg][ct][reg]);
                    }
                }
            }
        }
        // fused attn_dots: wave owns heads 2*wave, 2*wave+1
        const int h0 = 2 * wave, h1 = 2 * wave + 1;
        float alv[4], arv[4];
        #pragma unroll
        for (int ct = 0; ct < 4; ct++) {
            int col = c0 + ct * 16 + l15;
            alv[ct] = attn_l[my * D_DIM + col];
            arv[ct] = attn_r[my * D_DIM + col];
        }
        #pragma unroll
        for (int rg = 0; rg < 4; rg++) {
            #pragma unroll
            for (int reg = 0; reg < 4; reg++) {
                float e0 = acc[rg][0][reg] * alv[0] + acc[rg][1][reg] * alv[1];
                float e1 = acc[rg][2][reg] * alv[2] + acc[rg][3][reg] * alv[3];
                float q0 = acc[rg][0][reg] * arv[0] + acc[rg][1][reg] * arv[1];
                float q1 = acc[rg][2][reg] * arv[2] + acc[rg][3][reg] * arv[3];
                #pragma unroll
                for (int off = 1; off < 16; off <<= 1) {
                    e0 += __shfl_xor(e0, off);
                    e1 += __shfl_xor(e1, off);
                    q0 += __shfl_xor(q0, off);
                    q1 += __shfl_xor(q1, off);
                }
                int row = r0 + rg * 16 + lhi * 4 + reg;
                if (l15 == 0 && row < N_NODES) {
                    el[row * H_HEADS + h0] = e0;
                    el[row * H_HEADS + h1] = e1;
                    er[row * H_HEADS + h0] = q0;
                    er[row * H_HEADS + h1] = q1;
                }
            }
        }
    } else {
        // bucket sort, class g
        const int g = (blockIdx.x - GEMM_BX) + NRANGE * my;
        const int m = g / NRANGE, c = g % NRANGE;
        const int n = min(pcur[g], CAP2);
        const long long* p = pairs + (size_t)g * CAP2;
        const int gbase = g * CAP2;
        const int d0 = c * RSZ;
        int* rs = rs3 + m * N_NODES;
        int* re = re3 + m * N_NODES;
        const int t = threadIdx.x;

        __shared__ int hist[RSZ];
        __shared__ int cur[RSZ];
        __shared__ int part[256];

        for (int i = t; i < RSZ; i += 256) hist[i] = 0;
        __syncthreads();
        for (int i = t; i < n; i += 256) {
            int d = (int)(p[i] & 0xffffffff) - d0;
            atomicAdd(&hist[d], 1);
        }
        __syncthreads();
        int b4 = t * 4;
        int v0 = (b4 + 0 < RSZ) ? hist[b4 + 0] : 0;
        int v1 = (b4 + 1 < RSZ) ? hist[b4 + 1] : 0;
        int v2 = (b4 + 2 < RSZ) ? hist[b4 + 2] : 0;
        int v3 = (b4 + 3 < RSZ) ? hist[b4 + 3] : 0;
        int e1 = v0, e2 = v0 + v1, e3 = v0 + v1 + v2, tot = e3 + v3;
        part[t] = tot;
        __syncthreads();
        for (int off = 1; off < 256; off <<= 1) {
            int u = (t >= off) ? part[t - off] : 0;
            __syncthreads();
            part[t] += u;
            __syncthreads();
        }
        int cb = (t == 0) ? 0 : part[t - 1];
        int eo[4] = {cb, cb + e1, cb + e2, cb + e3};
        int vv[4] = {v0, v1, v2, v3};
        __syncthreads();
        #pragma unroll
        for (int k = 0; k < 4; k++) {
            int idx = b4 + k;
            if (idx < RSZ) {
                cur[idx] = eo[k];
                int node = d0 + idx;
                if (node < N_NODES) {
                    rs[node] = gbase + eo[k];
                    re[node] = gbase + eo[k] + vv[k];
                }
            }
        }
        __syncthreads();
        for (int i = t; i < n; i += 256) {
            long long v = p[i];
            int d = (int)(v & 0xffffffff) - d0;
            int slot = atomicAdd(&cur[d], 1);
            bsrc[gbase + slot] = (int)(v >> 32);
        }
    }
}

// ======= gather: 1 wave/node, 4 nodes/block, uint2 loads, 4-edge unroll =======
__global__ __launch_bounds__(256) void gather_z(const int* __restrict__ rs3,
                                                const int* __restrict__ re3,
                                                const int* __restrict__ bsrc,
                                                const float* __restrict__ el3,
                                                const float* __restrict__ er3,
                                                const uint2* __restrict__ featb2,
                                                const float* __restrict__ bias_all,
                                                uint2* __restrict__ zb2) {
    const int m = blockIdx.y;
    const float* el = el3 + (size_t)m * N_NODES * H_HEADS;
    const float* er = er3 + (size_t)m * N_NODES * H_HEADS;
    const uint2* featb = featb2 + (size_t)m * N_NODES * 64;
    const float* bias = bias_all + m * D_DIM;
    uint2* zb = zb2 + (size_t)m * N_NODES * 64;

    const int wid = threadIdx.x >> 6;
    const int l = threadIdx.x & 63;
    const int d = blockIdx.x * 4 + wid;
    const int hh = l >> 3;              // this lane's head; el load is an 8-way broadcast
    const int j0 = rs3[m * N_NODES + d], j1 = re3[m * N_NODES + d];
    const float erv = er[d * H_HEADS + hh];

    float den = 0.f, a0 = 0.f, a1 = 0.f, a2 = 0.f, a3 = 0.f;
    int j = j0;
    for (; j + 4 <= j1; j += 4) {
        int s0 = bsrc[j], s1 = bsrc[j + 1], s2 = bsrc[j + 2], s3 = bsrc[j + 3];
        float y0 = el[s0 * H_HEADS + hh] + erv;
        float y1 = el[s1 * H_HEADS + hh] + erv;
        float y2 = el[s2 * H_HEADS + hh] + erv;
        float y3 = el[s3 * H_HEADS + hh] + erv;
        uint2 w0 = featb[(size_t)s0 * 64 + l];
        uint2 w1 = featb[(size_t)s1 * 64 + l];
        uint2 w2 = featb[(size_t)s2 * 64 + l];
        uint2 w3 = featb[(size_t)s3 * 64 + l];
        y0 = fmaxf(y0, NEG_SLOPE * y0);
        y1 = fmaxf(y1, NEG_SLOPE * y1);
        y2 = fmaxf(y2, NEG_SLOPE * y2);
        y3 = fmaxf(y3, NEG_SLOPE * y3);
        float ex0 = __expf(y0), ex1 = __expf(y1), ex2 = __expf(y2), ex3 = __expf(y3);
        den += (ex0 + ex1) + (ex2 + ex3);
        a0 += ex0 * bflo(w0.x) + ex1 * bflo(w1.x) + ex2 * bflo(w2.x) + ex3 * bflo(w3.x);
        a1 += ex0 * bfhi(w0.x) + ex1 * bfhi(w1.x) + ex2 * bfhi(w2.x) + ex3 * bfhi(w3.x);
        a2 += ex0 * bflo(w0.y) + ex1 * bflo(w1.y) + ex2 * bflo(w2.y) + ex3 * bflo(w3.y);
        a3 += ex0 * bfhi(w0.y) + ex1 * bfhi(w1.y) + ex2 * bfhi(w2.y) + ex3 * bfhi(w3.y);
    }
    if (j + 2 <= j1) {
        int s0 = bsrc[j], s1 = bsrc[j + 1];
        float y0 = el[s0 * H_HEADS + hh] + erv;
        float y1 = el[s1 * H_HEADS + hh] + erv;
        uint2 w0 = featb[(size_t)s0 * 64 + l];
        uint2 w1 = featb[(size_t)s1 * 64 + l];
        y0 = fmaxf(y0, NEG_SLOPE * y0);
        y1 = fmaxf(y1, NEG_SLOPE * y1);
        float ex0 = __expf(y0), ex1 = __expf(y1);
        den += ex0 + ex1;
        a0 += ex0 * bflo(w0.x) + ex1 * bflo(w1.x);
        a1 += ex0 * bfhi(w0.x) + ex1 * bfhi(w1.x);
        a2 += ex0 * bflo(w0.y) + ex1 * bflo(w1.y);
        a3 += ex0 * bfhi(w0.y) + ex1 * bfhi(w1.y);
        j += 2;
    }
    if (j < j1) {
        int s = bsrc[j];
        float y = el[s * H_HEADS + hh] + erv;
        uint2 w = featb[(size_t)s * 64 + l];
        y = fmaxf(y, NEG_SLOPE * y);
        float ex = __expf(y);
        den += ex;
        a0 += ex * bflo(w.x); a1 += ex * bfhi(w.x);
        a2 += ex * bflo(w.y); a3 += ex * bfhi(w.y);
    }
    float inv = 1.f / (den == 0.f ? 1.f : den);
    float4 b4 = ((const float4*)bias)[l];
    float x0 = a0 * inv + b4.x;
    float x1 = a1 * inv + b4.y;
    float x2 = a2 * inv + b4.z;
    float x3 = a3 * inv + b4.w;
    x0 = x0 > 0.f ? x0 : expm1f(x0);
    x1 = x1 > 0.f ? x1 : expm1f(x1);
    x2 = x2 > 0.f ? x2 : expm1f(x2);
    x3 = x3 > 0.f ? x3 : expm1f(x3);
    uint2 r;
    r.x = pk_bf16(x0, x1);
    r.y = pk_bf16(x2, x3);
    zb[(size_t)d * 64 + l] = r;
}

// ======= semantic attention (all metapaths) via MFMA on bf16 z =======
__global__ __launch_bounds__(256) void semantic_mfma(const unsigned short* __restrict__ zb3,
                                                     const unsigned short* __restrict__ W1t,
                                                     const float* __restrict__ b1,
                                                     const float* __restrict__ W2,
                                                     float* __restrict__ wsum) {
    const int m = blockIdx.y;
    const unsigned short* zb = zb3 + (size_t)m * N_NODES * D_DIM;
    const int wave = threadIdx.x >> 6;
    const int lane = threadIdx.x & 63;
    const int l15 = lane & 15, lhi = lane >> 4;
    const int r0 = blockIdx.x * 64 + wave * 16;
    f32x4 acc[8] = {};

    for (int ks = 0; ks < 8; ++ks) {
        int row = r0 + l15;
        bf16x8 a = (row < N_NODES)
            ? *reinterpret_cast<const bf16x8*>(zb + (size_t)row * D_DIM + ks * 32 + lhi * 8)
            : zero_frag();
        #pragma unroll
        for (int ht = 0; ht < 8; ht++) {
            int col = ht * 16 + l15;
            bf16x8 b = *reinterpret_cast<const bf16x8*>(W1t + (size_t)col * D_DIM + ks * 32 + lhi * 8);
            acc[ht] = __builtin_amdgcn_mfma_f32_16x16x32_bf16(a, b, acc[ht], 0, 0, 0);
        }
    }
    float part = 0.f;
    #pragma unroll
    for (int ht = 0; ht < 8; ht++) {
        int col = ht * 16 + l15;
        float bb = b1[col], w2 = W2[col];
        #pragma unroll
        for (int reg = 0; reg < 4; reg++) {
            int row = r0 + lhi * 4 + reg;
            if (row < N_NODES) part += fast_tanh(acc[ht][reg] + bb) * w2;
        }
    }
    #pragma unroll
    for (int off = 1; off < 64; off <<= 1) part += __shfl_xor(part, off);
    if (lane == 0) atomicAdd(&wsum[m], part);
}

// ======= final: beta = softmax(wsum/N) inline; out = sum_m beta[m]*zb[m] =======
__global__ void final_mix(const unsigned* __restrict__ zb, const float* __restrict__ wsum,
                          float* __restrict__ out) {
    int i = blockIdx.x * blockDim.x + threadIdx.x;
    if (i >= N_NODES * (D_DIM / 2)) return;
    float v0 = wsum[0] / N_NODES, v1 = wsum[1] / N_NODES, v2 = wsum[2] / N_NODES;
    float mx = fmaxf(v0, fmaxf(v1, v2));
    float e0 = __expf(v0 - mx), e1 = __expf(v1 - mx), e2 = __expf(v2 - mx);
    float inv = 1.f / (e0 + e1 + e2);
    float b0 = e0 * inv, b1 = e1 * inv, b2 = e2 * inv;
    const size_t stride = (size_t)N_NODES * (D_DIM / 2);
    unsigned w0 = zb[i], w1 = zb[stride + i], w2 = zb[2 * stride + i];
    float2 r;
    r.x = b0 * bflo(w0) + b1 * bflo(w1) + b2 * bflo(w2);
    r.y = b0 * bfhi(w0) + b1 * bfhi(w1) + b2 * bfhi(w2);
    ((float2*)out)[i] = r;
}

extern "C" void kernel_launch(void* const* d_in, const int* in_sizes, int n_in,
                              void* d_out, int out_size, void* d_ws, size_t ws_size,
                              hipStream_t stream) {
    const float* h        = (const float*)d_in[0];
    const int*   eidx     = (const int*)d_in[1];
    const float* W        = (const float*)d_in[2];
    const float* attn_l   = (const float*)d_in[3];
    const float* attn_r   = (const float*)d_in[4];
    const float* bias     = (const float*)d_in[5];
    const float* sem_W1   = (const float*)d_in[6];
    const float* sem_b1   = (const float*)d_in[7];
    const float* sem_W2   = (const float*)d_in[8];
    float* out = (float*)d_out;

    float* ws = (float*)d_ws;
    float* wsum = ws;                                      // 8
    int* pcur   = (int*)(wsum + 8);                        // NCLASS
    float* el3  = (float*)(pcur + NCLASS);                 // M*N*H
    float* er3  = el3 + (size_t)M_PATHS * N_NODES * H_HEADS;
    unsigned short* featb3 = (unsigned short*)(er3 + (size_t)M_PATHS * N_NODES * H_HEADS);
    unsigned short* zb     = featb3 + (size_t)M_PATHS * N_NODES * D_DIM;
    unsigned short* Wt     = zb + (size_t)M_PATHS * N_NODES * D_DIM;
    unsigned short* W1t    = Wt + (size_t)M_PATHS * D_DIM * IN_F;
    long long* pairs = (long long*)(W1t + (size_t)HID_DIM * D_DIM);
    int* bsrc  = (int*)(pairs + (size_t)NCLASS * CAP2);
    int* rs3   = bsrc + (size_t)NCLASS * CAP2;
    int* re3   = rs3 + M_PATHS * N_NODES;

    hipMemsetAsync(wsum, 0, (8 + NCLASS) * sizeof(int), stream);

    prep<<<dim3(NCHUNK + TBLK, M_PATHS), 256, 0, stream>>>(
        eidx, W, sem_W1, pcur, pairs, Wt, W1t);

    gemm_bucket<<<dim3(GEMM_BX + NRANGE, M_PATHS), 256, 0, stream>>>(
        h, Wt, attn_l, attn_r, featb3, el3, er3, pairs, pcur, bsrc, rs3, re3);

    gather_z<<<dim3(N_NODES / 4, M_PATHS), 256, 0, stream>>>(
        rs3, re3, bsrc, el3, er3, (const uint2*)featb3, bias, (uint2*)zb);

    semantic_mfma<<<dim3((N_NODES + 63) / 64, M_PATHS), 256, 0, stream>>>(
        zb, W1t, sem_b1, sem_W2, wsum);

    final_mix<<<(N_NODES * (D_DIM / 2) + 255) / 256, 256, 0, stream>>>(
        (const unsigned*)zb, wsum, out);
}

// Round 18
// 514.063 us; speedup vs baseline: 1.1076x; 1.1076x over previous
//
#include <hip/hip_runtime.h>
#include <hip/hip_bf16.h>
#include <math.h>
#include <string.h>

#define N_NODES 50000
#define E_EDGES 800000
#define M_PATHS 3
#define IN_F    128
#define H_HEADS 8
#define O_DIM   32
#define D_DIM   256   // H*O
#define HID_DIM 128
#define NEG_SLOPE 0.2f
#define NRANGE   64
#define RSZ      782                   // ceil(50000/64)
#define NCLASS   (M_PATHS * NRANGE)    // 192
#define CAP2     16384
#define CHUNK    2048
#define NCHUNK   ((E_EDGES + CHUNK - 1) / CHUNK)   // 391
#define TBLK     171                   // transpose blocks per metapath row
#define GEMM_BX  ((N_NODES + 63) / 64) // 782

typedef __attribute__((ext_vector_type(8))) short bf16x8;
typedef __attribute__((ext_vector_type(4))) float f32x4;

__device__ __forceinline__ float bflo(unsigned w) { return __uint_as_float(w << 16); }
__device__ __forceinline__ float bfhi(unsigned w) { return __uint_as_float(w & 0xffff0000u); }

__device__ __forceinline__ unsigned short f2bf(float f) {
    __hip_bfloat16 hb = __float2bfloat16(f);
    unsigned short us;
    memcpy(&us, &hb, 2);
    return us;
}
__device__ __forceinline__ unsigned pk_bf16(float a, float b) {
    return (unsigned)f2bf(a) | ((unsigned)f2bf(b) << 16);
}
__device__ __forceinline__ float fast_tanh(float x) {
    float e = __expf(2.f * x);        // |x| < ~6 here; no overflow
    return (e - 1.f) / (e + 1.f);
}

__device__ __forceinline__ bf16x8 cvt_frag(const float* __restrict__ p) {
    union { unsigned short u[8]; bf16x8 v; } r;
    const float4 f0 = *reinterpret_cast<const float4*>(p);
    const float4 f1 = *reinterpret_cast<const float4*>(p + 4);
    r.u[0] = f2bf(f0.x); r.u[1] = f2bf(f0.y); r.u[2] = f2bf(f0.z); r.u[3] = f2bf(f0.w);
    r.u[4] = f2bf(f1.x); r.u[5] = f2bf(f1.y); r.u[6] = f2bf(f1.z); r.u[7] = f2bf(f1.w);
    return r.v;
}
__device__ __forceinline__ bf16x8 zero_frag() {
    union { unsigned short u[8]; bf16x8 v; } r = {};
    return r.v;
}

// ======= prep: partition_edges (x < NCHUNK) + weight transposes (x >= NCHUNK) =======
__global__ __launch_bounds__(256) void prep(const int* __restrict__ eidx,
                                            const float* __restrict__ W,
                                            const float* __restrict__ W1,
                                            int* __restrict__ pcur,
                                            long long* __restrict__ pairs,
                                            unsigned short* __restrict__ Wt,
                                            unsigned short* __restrict__ W1t) {
    const int m = blockIdx.y;
    if (blockIdx.x < NCHUNK) {
        const int e0 = blockIdx.x * CHUNK;
        const int n = min(CHUNK, E_EDGES - e0);
        const int* src = eidx + (size_t)m * 2 * E_EDGES;
        const int* dst = src + E_EDGES;

        __shared__ int lcnt[NRANGE], lbase[NRANGE], lidx[NRANGE];
        for (int i = threadIdx.x; i < NRANGE; i += 256) lcnt[i] = 0;
        __syncthreads();

        int ss[8], cs[8];
        #pragma unroll
        for (int k = 0; k < 8; k++) {
            int o = k * 256 + threadIdx.x;
            if (o < n) {
                int e = e0 + o;
                int d = __builtin_nontemporal_load(dst + e);
                int s = __builtin_nontemporal_load(src + e);
                int c = d / RSZ;
                ss[k] = s; cs[k] = c | (d << 8);
                atomicAdd(&lcnt[c], 1);
            } else cs[k] = -1;
        }
        __syncthreads();
        for (int i = threadIdx.x; i < NRANGE; i += 256) {
            int cnt = lcnt[i];
            lbase[i] = (cnt > 0) ? atomicAdd(&pcur[m * NRANGE + i], cnt) : 0;
            lidx[i] = 0;
        }
        __syncthreads();
        #pragma unroll
        for (int k = 0; k < 8; k++) {
            if (cs[k] >= 0) {
                int c = cs[k] & 63;
                int d = cs[k] >> 8;
                int slot = lbase[c] + atomicAdd(&lidx[c], 1);
                if (slot < CAP2) {
                    long long p = ((long long)ss[k] << 32) | (unsigned)d;
                    pairs[(size_t)(m * NRANGE + c) * CAP2 + slot] = p;
                }
            }
        }
    } else {
        int t = blockIdx.x - NCHUNK + TBLK * m;
        if (t < 384) {              // W[m'] : [128][256] -> Wt[m'] : [256][128]
            int i = t * 256 + threadIdx.x;
            int mm = i >> 15, r = i & 32767;
            int k = r >> 8, c = r & 255;
            Wt[(size_t)mm * 32768 + c * IN_F + k] = f2bf(W[i]);
        } else if (t < 512) {       // sem_W1 : [256][128] -> W1t : [128][256]
            int r = (t - 384) * 256 + threadIdx.x;
            int k = r >> 7, c = r & 127;
            W1t[c * D_DIM + k] = f2bf(W1[r]);
        }
    }
}

// ======= gemm (+attn epilogue) for x < GEMM_BX; bucket_sort for x >= GEMM_BX =======
__global__ __launch_bounds__(256) void gemm_bucket(const float* __restrict__ hall,
                                                   const unsigned short* __restrict__ Wtall,
                                                   const float* __restrict__ attn_l,
                                                   const float* __restrict__ attn_r,
                                                   unsigned short* __restrict__ featb3,
                                                   float* __restrict__ el3,
                                                   float* __restrict__ er3,
                                                   const long long* __restrict__ pairs,
                                                   const int* __restrict__ pcur,
                                                   int* __restrict__ bsrc,
                                                   int* __restrict__ rs3,
                                                   int* __restrict__ re3) {
    const int my = blockIdx.y;
    if (blockIdx.x < GEMM_BX) {
        const float* h = hall + (size_t)my * N_NODES * IN_F;
        const unsigned short* Wt = Wtall + (size_t)my * D_DIM * IN_F;
        unsigned short* featb = featb3 + (size_t)my * N_NODES * D_DIM;
        float* el = el3 + (size_t)my * N_NODES * H_HEADS;
        float* er = er3 + (size_t)my * N_NODES * H_HEADS;

        const int wave = threadIdx.x >> 6;
        const int lane = threadIdx.x & 63;
        const int l15 = lane & 15, lhi = lane >> 4;
        const int r0 = blockIdx.x * 64;
        const int c0 = wave * 64;
        f32x4 acc[4][4] = {};

        for (int ks = 0; ks < 4; ++ks) {
            bf16x8 a[4], b[4];
            #pragma unroll
            for (int rg = 0; rg < 4; rg++) {
                int row = r0 + rg * 16 + l15;
                a[rg] = (row < N_NODES) ? cvt_frag(h + (size_t)row * IN_F + ks * 32 + lhi * 8)
                                        : zero_frag();
            }
            #pragma unroll
            for (int ct = 0; ct < 4; ct++) {
                int col = c0 + ct * 16 + l15;
                b[ct] = *reinterpret_cast<const bf16x8*>(Wt + (size_t)col * IN_F + ks * 32 + lhi * 8);
            }
            #pragma unroll
            for (int rg = 0; rg < 4; rg++)
                #pragma unroll
                for (int ct = 0; ct < 4; ct++)
                    acc[rg][ct] = __builtin_amdgcn_mfma_f32_16x16x32_bf16(a[rg], b[ct], acc[rg][ct], 0, 0, 0);
        }
        #pragma unroll
        for (int rg = 0; rg < 4; rg++) {
            #pragma unroll
            for (int reg = 0; reg < 4; reg++) {
                int row = r0 + rg * 16 + lhi * 4 + reg;
                if (row < N_NODES) {
                    #pragma unroll
                    for (int ct = 0; ct < 4; ct++) {
                        int col = c0 + ct * 16 + l15;
                        featb[(size_t)row * D_DIM + col] = f2bf(acc[rg][ct][reg]);
                    }
                }
            }
        }
        // fused attn_dots: wave owns heads 2*wave, 2*wave+1
        const int h0 = 2 * wave, h1 = 2 * wave + 1;
        float alv[4], arv[4];
        #pragma unroll
        for (int ct = 0; ct < 4; ct++) {
            int col = c0 + ct * 16 + l15;
            alv[ct] = attn_l[my * D_DIM + col];
            arv[ct] = attn_r[my * D_DIM + col];
        }
        #pragma unroll
        for (int rg = 0; rg < 4; rg++) {
            #pragma unroll
            for (int reg = 0; reg < 4; reg++) {
                float e0 = acc[rg][0][reg] * alv[0] + acc[rg][1][reg] * alv[1];
                float e1 = acc[rg][2][reg] * alv[2] + acc[rg][3][reg] * alv[3];
                float q0 = acc[rg][0][reg] * arv[0] + acc[rg][1][reg] * arv[1];
                float q1 = acc[rg][2][reg] * arv[2] + acc[rg][3][reg] * arv[3];
                #pragma unroll
                for (int off = 1; off < 16; off <<= 1) {
                    e0 += __shfl_xor(e0, off);
                    e1 += __shfl_xor(e1, off);
                    q0 += __shfl_xor(q0, off);
                    q1 += __shfl_xor(q1, off);
                }
                int row = r0 + rg * 16 + lhi * 4 + reg;
                if (l15 == 0 && row < N_NODES) {
                    el[row * H_HEADS + h0] = e0;
                    el[row * H_HEADS + h1] = e1;
                    er[row * H_HEADS + h0] = q0;
                    er[row * H_HEADS + h1] = q1;
                }
            }
        }
    } else {
        // bucket sort, class g
        const int g = (blockIdx.x - GEMM_BX) + NRANGE * my;
        const int m = g / NRANGE, c = g % NRANGE;
        const int n = min(pcur[g], CAP2);
        const long long* p = pairs + (size_t)g * CAP2;
        const int gbase = g * CAP2;
        const int d0 = c * RSZ;
        int* rs = rs3 + m * N_NODES;
        int* re = re3 + m * N_NODES;
        const int t = threadIdx.x;

        __shared__ int hist[RSZ];
        __shared__ int cur[RSZ];
        __shared__ int part[256];

        for (int i = t; i < RSZ; i += 256) hist[i] = 0;
        __syncthreads();
        for (int i = t; i < n; i += 256) {
            int d = (int)(p[i] & 0xffffffff) - d0;
            atomicAdd(&hist[d], 1);
        }
        __syncthreads();
        int b4 = t * 4;
        int v0 = (b4 + 0 < RSZ) ? hist[b4 + 0] : 0;
        int v1 = (b4 + 1 < RSZ) ? hist[b4 + 1] : 0;
        int v2 = (b4 + 2 < RSZ) ? hist[b4 + 2] : 0;
        int v3 = (b4 + 3 < RSZ) ? hist[b4 + 3] : 0;
        int e1 = v0, e2 = v0 + v1, e3 = v0 + v1 + v2, tot = e3 + v3;
        part[t] = tot;
        __syncthreads();
        for (int off = 1; off < 256; off <<= 1) {
            int u = (t >= off) ? part[t - off] : 0;
            __syncthreads();
            part[t] += u;
            __syncthreads();
        }
        int cb = (t == 0) ? 0 : part[t - 1];
        int eo[4] = {cb, cb + e1, cb + e2, cb + e3};
        int vv[4] = {v0, v1, v2, v3};
        __syncthreads();
        #pragma unroll
        for (int k = 0; k < 4; k++) {
            int idx = b4 + k;
            if (idx < RSZ) {
                cur[idx] = eo[k];
                int node = d0 + idx;
                if (node < N_NODES) {
                    rs[node] = gbase + eo[k];
                    re[node] = gbase + eo[k] + vv[k];
                }
            }
        }
        __syncthreads();
        for (int i = t; i < n; i += 256) {
            long long v = p[i];
            int d = (int)(v & 0xffffffff) - d0;
            int slot = atomicAdd(&cur[d], 1);
            bsrc[gbase + slot] = (int)(v >> 32);
        }
    }
}

// ======= gather + in-block semantic attention =======
__global__ __launch_bounds__(256) void gather_sem(const int* __restrict__ rs3,
                                                  const int* __restrict__ re3,
                                                  const int* __restrict__ bsrc,
                                                  const float* __restrict__ el3,
                                                  const float* __restrict__ er3,
                                                  const uint4* __restrict__ featb4,
                                                  const float* __restrict__ bias_all,
                                                  const unsigned short* __restrict__ W1t,
                                                  const float* __restrict__ b1v,
                                                  const float* __restrict__ W2v,
                                                  uint4* __restrict__ zb4,
                                                  float* __restrict__ wsum) {
    const int m = blockIdx.y;
    const float* el = el3 + (size_t)m * N_NODES * H_HEADS;
    const float* er = er3 + (size_t)m * N_NODES * H_HEADS;
    const uint4* featb = featb4 + (size_t)m * N_NODES * 32;
    const float* bias = bias_all + m * D_DIM;
    uint4* zb = zb4 + (size_t)m * N_NODES * 32;

    const int wid = threadIdx.x >> 6;
    const int half = (threadIdx.x >> 5) & 1;
    const int l = threadIdx.x & 31;
    const int nl = wid * 2 + half;            // node-local 0..7
    const int d = blockIdx.x * 8 + nl;
    const int hh = l >> 2;
    const int j0 = rs3[m * N_NODES + d], j1 = re3[m * N_NODES + d];
    const float erv = er[d * H_HEADS + hh];

    float den = 0.f;
    float a0 = 0.f, a1 = 0.f, a2 = 0.f, a3 = 0.f, a4 = 0.f, a5 = 0.f, a6 = 0.f, a7 = 0.f;
    int j = j0;
    for (; j + 4 <= j1; j += 4) {
        int s0 = bsrc[j], s1 = bsrc[j + 1], s2 = bsrc[j + 2], s3 = bsrc[j + 3];
        float y0 = el[s0 * H_HEADS + hh] + erv;
        float y1 = el[s1 * H_HEADS + hh] + erv;
        float y2 = el[s2 * H_HEADS + hh] + erv;
        float y3 = el[s3 * H_HEADS + hh] + erv;
        uint4 w0 = featb[(size_t)s0 * 32 + l];
        uint4 w1 = featb[(size_t)s1 * 32 + l];
        uint4 w2 = featb[(size_t)s2 * 32 + l];
        uint4 w3 = featb[(size_t)s3 * 32 + l];
        y0 = fmaxf(y0, NEG_SLOPE * y0);
        y1 = fmaxf(y1, NEG_SLOPE * y1);
        y2 = fmaxf(y2, NEG_SLOPE * y2);
        y3 = fmaxf(y3, NEG_SLOPE * y3);
        float ex0 = __expf(y0), ex1 = __expf(y1), ex2 = __expf(y2), ex3 = __expf(y3);
        den += (ex0 + ex1) + (ex2 + ex3);
        a0 += ex0 * bflo(w0.x) + ex1 * bflo(w1.x) + ex2 * bflo(w2.x) + ex3 * bflo(w3.x);
        a1 += ex0 * bfhi(w0.x) + ex1 * bfhi(w1.x) + ex2 * bfhi(w2.x) + ex3 * bfhi(w3.x);
        a2 += ex0 * bflo(w0.y) + ex1 * bflo(w1.y) + ex2 * bflo(w2.y) + ex3 * bflo(w3.y);
        a3 += ex0 * bfhi(w0.y) + ex1 * bfhi(w1.y) + ex2 * bfhi(w2.y) + ex3 * bfhi(w3.y);
        a4 += ex0 * bflo(w0.z) + ex1 * bflo(w1.z) + ex2 * bflo(w2.z) + ex3 * bflo(w3.z);
        a5 += ex0 * bfhi(w0.z) + ex1 * bfhi(w1.z) + ex2 * bfhi(w2.z) + ex3 * bfhi(w3.z);
        a6 += ex0 * bflo(w0.w) + ex1 * bflo(w1.w) + ex2 * bflo(w2.w) + ex3 * bflo(w3.w);
        a7 += ex0 * bfhi(w0.w) + ex1 * bfhi(w1.w) + ex2 * bfhi(w2.w) + ex3 * bfhi(w3.w);
    }
    for (; j < j1; ++j) {
        int s = bsrc[j];
        float y = el[s * H_HEADS + hh] + erv;
        uint4 w = featb[(size_t)s * 32 + l];
        y = fmaxf(y, NEG_SLOPE * y);
        float ex = __expf(y);
        den += ex;
        a0 += ex * bflo(w.x); a1 += ex * bfhi(w.x);
        a2 += ex * bflo(w.y); a3 += ex * bfhi(w.y);
        a4 += ex * bflo(w.z); a5 += ex * bfhi(w.z);
        a6 += ex * bflo(w.w); a7 += ex * bfhi(w.w);
    }
    float inv = 1.f / (den == 0.f ? 1.f : den);
    float4 b40 = ((const float4*)bias)[2 * l];
    float4 b41 = ((const float4*)bias)[2 * l + 1];
    float x0 = a0 * inv + b40.x, x1 = a1 * inv + b40.y;
    float x2 = a2 * inv + b40.z, x3 = a3 * inv + b40.w;
    float x4 = a4 * inv + b41.x, x5 = a5 * inv + b41.y;
    float x6 = a6 * inv + b41.z, x7 = a7 * inv + b41.w;
    x0 = x0 > 0.f ? x0 : expm1f(x0);
    x1 = x1 > 0.f ? x1 : expm1f(x1);
    x2 = x2 > 0.f ? x2 : expm1f(x2);
    x3 = x3 > 0.f ? x3 : expm1f(x3);
    x4 = x4 > 0.f ? x4 : expm1f(x4);
    x5 = x5 > 0.f ? x5 : expm1f(x5);
    x6 = x6 > 0.f ? x6 : expm1f(x6);
    x7 = x7 > 0.f ? x7 : expm1f(x7);
    uint4 r;
    r.x = pk_bf16(x0, x1);
    r.y = pk_bf16(x2, x3);
    r.z = pk_bf16(x4, x5);
    r.w = pk_bf16(x6, x7);
    zb[(size_t)d * 32 + l] = r;

    // ---- fused semantic attention on this block's 8 z-rows ----
    __shared__ uint4 zs4[8 * 33];             // 8 rows x 32 uint4, pad 1
    __shared__ float sred[4];
    zs4[nl * 33 + l] = r;
    __syncthreads();

    const int lane = threadIdx.x & 63;
    const int row16 = lane & 15, kslot = lane >> 4;
    f32x4 sacc[2] = {};
    for (int ks = 0; ks < 8; ++ks) {
        bf16x8 a = (row16 < 8)
            ? *reinterpret_cast<const bf16x8*>(&zs4[row16 * 33 + ks * 4 + kslot])
            : zero_frag();
        #pragma unroll
        for (int q = 0; q < 2; q++) {
            int col = (wid * 2 + q) * 16 + row16;
            bf16x8 b = *reinterpret_cast<const bf16x8*>(W1t + (size_t)col * D_DIM + ks * 32 + kslot * 8);
            sacc[q] = __builtin_amdgcn_mfma_f32_16x16x32_bf16(a, b, sacc[q], 0, 0, 0);
        }
    }
    float part = 0.f;
    #pragma unroll
    for (int q = 0; q < 2; q++) {
        int col = (wid * 2 + q) * 16 + row16;
        float bb = b1v[col], w2 = W2v[col];
        #pragma unroll
        for (int reg = 0; reg < 4; reg++) {
            int prow = (lane >> 4) * 4 + reg;
            if (prow < 8) part += fast_tanh(sacc[q][reg] + bb) * w2;
        }
    }
    #pragma unroll
    for (int off = 1; off < 64; off <<= 1) part += __shfl_xor(part, off);
    if (lane == 0) sred[wid] = part;
    __syncthreads();
    if (threadIdx.x == 0)
        atomicAdd(&wsum[m], sred[0] + sred[1] + sred[2] + sred[3]);
}

// ======= final: beta = softmax(wsum/N) inline; out = sum_m beta[m]*zb[m] =======
__global__ void final_mix(const unsigned* __restrict__ zb, const float* __restrict__ wsum,
                          float* __restrict__ out) {
    int i = blockIdx.x * blockDim.x + threadIdx.x;
    if (i >= N_NODES * (D_DIM / 2)) return;
    float v0 = wsum[0] / N_NODES, v1 = wsum[1] / N_NODES, v2 = wsum[2] / N_NODES;
    float mx = fmaxf(v0, fmaxf(v1, v2));
    float e0 = __expf(v0 - mx), e1 = __expf(v1 - mx), e2 = __expf(v2 - mx);
    float inv = 1.f / (e0 + e1 + e2);
    float b0 = e0 * inv, b1 = e1 * inv, b2 = e2 * inv;
    const size_t stride = (size_t)N_NODES * (D_DIM / 2);
    unsigned w0 = zb[i], w1 = zb[stride + i], w2 = zb[2 * stride + i];
    float2 r;
    r.x = b0 * bflo(w0) + b1 * bflo(w1) + b2 * bflo(w2);
    r.y = b0 * bfhi(w0) + b1 * bfhi(w1) + b2 * bfhi(w2);
    ((float2*)out)[i] = r;
}

extern "C" void kernel_launch(void* const* d_in, const int* in_sizes, int n_in,
                              void* d_out, int out_size, void* d_ws, size_t ws_size,
                              hipStream_t stream) {
    const float* h        = (const float*)d_in[0];
    const int*   eidx     = (const int*)d_in[1];
    const float* W        = (const float*)d_in[2];
    const float* attn_l   = (const float*)d_in[3];
    const float* attn_r   = (const float*)d_in[4];
    const float* bias     = (const float*)d_in[5];
    const float* sem_W1   = (const float*)d_in[6];
    const float* sem_b1   = (const float*)d_in[7];
    const float* sem_W2   = (const float*)d_in[8];
    float* out = (float*)d_out;

    float* ws = (float*)d_ws;
    float* wsum = ws;                                      // 8
    int* pcur   = (int*)(wsum + 8);                        // NCLASS
    float* el3  = (float*)(pcur + NCLASS);                 // M*N*H
    float* er3  = el3 + (size_t)M_PATHS * N_NODES * H_HEADS;
    unsigned short* featb3 = (unsigned short*)(er3 + (size_t)M_PATHS * N_NODES * H_HEADS);
    unsigned short* zb     = featb3 + (size_t)M_PATHS * N_NODES * D_DIM;
    unsigned short* Wt     = zb + (size_t)M_PATHS * N_NODES * D_DIM;
    unsigned short* W1t    = Wt + (size_t)M_PATHS * D_DIM * IN_F;
    long long* pairs = (long long*)(W1t + (size_t)HID_DIM * D_DIM);
    int* bsrc  = (int*)(pairs + (size_t)NCLASS * CAP2);
    int* rs3   = bsrc + (size_t)NCLASS * CAP2;
    int* re3   = rs3 + M_PATHS * N_NODES;

    hipMemsetAsync(wsum, 0, (8 + NCLASS) * sizeof(int), stream);

    prep<<<dim3(NCHUNK + TBLK, M_PATHS), 256, 0, stream>>>(
        eidx, W, sem_W1, pcur, pairs, Wt, W1t);

    gemm_bucket<<<dim3(GEMM_BX + NRANGE, M_PATHS), 256, 0, stream>>>(
        h, Wt, attn_l, attn_r, featb3, el3, er3, pairs, pcur, bsrc, rs3, re3);

    gather_sem<<<dim3(N_NODES / 8, M_PATHS), 256, 0, stream>>>(
        rs3, re3, bsrc, el3, er3, (const uint4*)featb3, bias,
        W1t, sem_b1, sem_W2, (uint4*)zb, wsum);

    final_mix<<<(N_NODES * (D_DIM / 2) + 255) / 256, 256, 0, stream>>>(
        (const unsigned*)zb, wsum, out);
}